// Round 1
// baseline (567.466 us; speedup 1.0000x reference)
//
#include <hip/hip_runtime.h>
#include <math.h>

// Problem constants
constexpr int Uc = 512;
constexpr int Pc = 1024;
constexpr int Dc = 128;
constexpr int Hc = 256;
constexpr int Ec = 98304;
constexpr int Nc = 1536;   // U + P

// ---------------- CSR construction ----------------

__global__ void k_zero_deg(int* deg) {
    int i = blockIdx.x * 256 + threadIdx.x;
    if (i < Nc) deg[i] = 0;
}

__global__ void k_hist(const int* __restrict__ dst, int* __restrict__ deg) {
    int e = blockIdx.x * 256 + threadIdx.x;
    if (e < Ec) atomicAdd(&deg[dst[e]], 1);
}

// Single block, 256 threads. Exclusive scan of per-node edge counts (6 per thread),
// also computes dis[i] = rsqrt(deg_edges + 1)  (the +1 is the self-loop).
__global__ void k_scan(const int* __restrict__ deg, int* __restrict__ offs,
                       int* __restrict__ cursor, float* __restrict__ dis) {
    __shared__ int partial[256];
    int t = threadIdx.x;
    int base = t * 6;
    int v[6];
    int s = 0;
#pragma unroll
    for (int j = 0; j < 6; j++) { v[j] = deg[base + j]; s += v[j]; }
    partial[t] = s;
    __syncthreads();
    // inclusive Hillis-Steele scan over 256 partials
    for (int off = 1; off < 256; off <<= 1) {
        int x = partial[t];
        int y = (t >= off) ? partial[t - off] : 0;
        __syncthreads();
        partial[t] = x + y;
        __syncthreads();
    }
    int run = (t == 0) ? 0 : partial[t - 1];
#pragma unroll
    for (int j = 0; j < 6; j++) {
        offs[base + j] = run;
        cursor[base + j] = run;
        dis[base + j] = rsqrtf((float)(v[j] + 1));
        run += v[j];
    }
    if (t == 255) offs[Nc] = run;
}

__global__ void k_scatter(const int* __restrict__ src, const int* __restrict__ dst,
                          int* __restrict__ cursor, int* __restrict__ col) {
    int e = blockIdx.x * 256 + threadIdx.x;
    if (e < Ec) {
        int p = atomicAdd(&cursor[dst[e]], 1);
        col[p] = src[e];
    }
}

// ---------------- node features ----------------

__global__ void k_build_x(const int* __restrict__ uid, const int* __restrict__ pid,
                          const float* __restrict__ ue, const float* __restrict__ pe,
                          float* __restrict__ x0) {
    int i = blockIdx.x;       // node
    int t = threadIdx.x;      // 128 threads = D
    if (i < Uc) x0[i * Dc + t] = ue[uid[i] * Dc + t];
    else        x0[i * Dc + t] = pe[pid[i - Uc] * Dc + t];
}

// ---------------- generic small GEMM:  Y[n,M] = X[n,K] @ W[K,M] (+bias) (+relu) ----
// Block: 256 threads handles 16 rows x M cols. n must be a multiple of 16.
template <int K>
__global__ void k_gemm(const float* __restrict__ X, const float* __restrict__ W,
                       const float* __restrict__ bias, float* __restrict__ Y,
                       int M, int do_relu) {
    __shared__ float xs[16 * K];
    int t = threadIdx.x;
    int r0 = blockIdx.x * 16;
    for (int idx = t; idx < 16 * K; idx += 256) {
        int r = idx / K, k = idx % K;
        xs[idx] = X[(r0 + r) * K + k];
    }
    __syncthreads();
    for (int j = t; j < M; j += 256) {
        float acc[16];
#pragma unroll
        for (int r = 0; r < 16; r++) acc[r] = 0.f;
        for (int k = 0; k < K; k++) {
            float w = W[k * M + j];
#pragma unroll
            for (int r = 0; r < 16; r++) acc[r] += xs[r * K + k] * w;
        }
        float b = bias ? bias[j] : 0.f;
#pragma unroll
        for (int r = 0; r < 16; r++) {
            float v = acc[r] + b;
            if (do_relu) v = fmaxf(v, 0.f);
            Y[(r0 + r) * M + j] = v;
        }
    }
}

// ---------------- GCN gather (SpMM by dst) + bias + relu ----------------
// One block per node, 256 threads (one per feature).
__global__ void k_gcn_gather(const float* __restrict__ h, const int* __restrict__ offs,
                             const int* __restrict__ col, const float* __restrict__ dis,
                             const float* __restrict__ bias, float* __restrict__ out) {
    int i = blockIdx.x;
    int f = threadIdx.x;
    float di = dis[i];
    float acc = h[i * Hc + f] * di * di;   // self-loop
    int e = offs[i], e1 = offs[i + 1];
    // 4x unrolled for ILP
    for (; e + 4 <= e1; e += 4) {
        int s0 = col[e], s1 = col[e + 1], s2 = col[e + 2], s3 = col[e + 3];
        float n0 = dis[s0] * di, n1 = dis[s1] * di, n2 = dis[s2] * di, n3 = dis[s3] * di;
        float h0 = h[s0 * Hc + f], h1 = h[s1 * Hc + f];
        float h2 = h[s2 * Hc + f], h3 = h[s3 * Hc + f];
        acc += h0 * n0 + h1 * n1 + h2 * n2 + h3 * n3;
    }
    for (; e < e1; e++) {
        int s = col[e];
        acc += h[s * Hc + f] * (dis[s] * di);
    }
    out[i * Hc + f] = fmaxf(acc + bias[f], 0.f);
}

// ---------------- predictor: pred[u,p] = sigmoid( sum_k relu(Au+Ap)*w + bq2 ) ------
// Block: 64 users x 64 papers, 256 threads, each thread 4x4 pairs.
__global__ void k_pred(const float* __restrict__ Au, const float* __restrict__ Ap,
                       const float* __restrict__ Wq2, const float* __restrict__ bq2,
                       float* __restrict__ out) {
    __shared__ float au_s[64][33];
    __shared__ float ap_s[64][33];
    __shared__ float w_s[Hc];
    int t = threadIdx.x;
    int ub = blockIdx.x * 64;
    int pb = blockIdx.y * 64;
    int tu = t >> 4, tp = t & 15;
    float acc[4][4] = {};
    w_s[t] = Wq2[t];
    for (int k0 = 0; k0 < Hc; k0 += 32) {
        __syncthreads();
        for (int idx = t; idx < 64 * 32; idx += 256) {
            int r = idx >> 5, kk = idx & 31;
            au_s[r][kk] = Au[(ub + r) * Hc + k0 + kk];
            ap_s[r][kk] = Ap[(pb + r) * Hc + k0 + kk];
        }
        __syncthreads();
#pragma unroll 8
        for (int kk = 0; kk < 32; kk++) {
            float w = w_s[k0 + kk];
            float av[4], pv[4];
#pragma unroll
            for (int r = 0; r < 4; r++) av[r] = au_s[tu * 4 + r][kk];
#pragma unroll
            for (int c = 0; c < 4; c++) pv[c] = ap_s[tp * 4 + c][kk];
#pragma unroll
            for (int r = 0; r < 4; r++)
#pragma unroll
                for (int c = 0; c < 4; c++)
                    acc[r][c] += fmaxf(av[r] + pv[c], 0.f) * w;
        }
    }
    float bq = bq2[0];
#pragma unroll
    for (int r = 0; r < 4; r++) {
        int u = ub + tu * 4 + r;
        float4 o;
        float* po = (float*)&o;
#pragma unroll
        for (int c = 0; c < 4; c++) {
            float s = acc[r][c] + bq;
            po[c] = 1.f / (1.f + __expf(-s));
        }
        *(float4*)&out[u * Pc + pb + tp * 4] = o;
    }
}

// ---------------- launcher ----------------

extern "C" void kernel_launch(void* const* d_in, const int* in_sizes, int n_in,
                              void* d_out, int out_size, void* d_ws, size_t ws_size,
                              hipStream_t stream) {
    const int*   uid = (const int*)d_in[0];
    const int*   pid = (const int*)d_in[1];
    const int*   ei  = (const int*)d_in[2];   // [2,E]: src = ei[0..E), dst = ei[E..2E)
    // d_in[3]: user_paper_interactions — unused by the reference forward
    const float* ue  = (const float*)d_in[4];
    const float* pe  = (const float*)d_in[5];
    const float* W0  = (const float*)d_in[6];  const float* b0 = (const float*)d_in[7];
    const float* W1  = (const float*)d_in[8];  const float* b1 = (const float*)d_in[9];
    const float* W2  = (const float*)d_in[10]; const float* b2 = (const float*)d_in[11];
    const float* Wu  = (const float*)d_in[12]; const float* bu = (const float*)d_in[13];
    const float* Wp  = (const float*)d_in[14]; const float* bp = (const float*)d_in[15];
    const float* Wq1 = (const float*)d_in[16]; const float* bq1 = (const float*)d_in[17];
    const float* Wq2 = (const float*)d_in[18]; const float* bq2 = (const float*)d_in[19];

    const int* e_src = ei;
    const int* e_dst = ei + Ec;

    char* w = (char*)d_ws;
    auto alloc = [&](size_t bytes) { char* p = w; w += (bytes + 255) & ~size_t(255); return p; };
    int*   deg    = (int*)alloc(Nc * 4);
    int*   offs   = (int*)alloc((Nc + 1) * 4);
    int*   cursor = (int*)alloc(Nc * 4);
    int*   col    = (int*)alloc(Ec * 4);
    float* dis    = (float*)alloc(Nc * 4);
    float* x0     = (float*)alloc((size_t)Nc * Dc * 4);
    float* xA     = (float*)alloc((size_t)Nc * Hc * 4);
    float* Hbuf   = (float*)alloc((size_t)Nc * Hc * 4);
    float* uf     = (float*)alloc((size_t)Uc * Dc * 4);
    float* pf     = (float*)alloc((size_t)Pc * Dc * 4);
    float* Au     = (float*)alloc((size_t)Uc * Hc * 4);
    float* Ap     = (float*)alloc((size_t)Pc * Hc * 4);
    float* pred   = (float*)d_out;

    // CSR by dst
    k_zero_deg<<<(Nc + 255) / 256, 256, 0, stream>>>(deg);
    k_hist<<<Ec / 256, 256, 0, stream>>>(e_dst, deg);
    k_scan<<<1, 256, 0, stream>>>(deg, offs, cursor, dis);
    k_scatter<<<Ec / 256, 256, 0, stream>>>(e_src, e_dst, cursor, col);

    // x0 = [user_emb[uid]; paper_emb[pid]]
    k_build_x<<<Nc, Dc, 0, stream>>>(uid, pid, ue, pe, x0);

    // Layer 0: H = x0 @ W0 ; xA = relu(gather(H) + b0)
    k_gemm<Dc><<<Nc / 16, 256, 0, stream>>>(x0, W0, nullptr, Hbuf, Hc, 0);
    k_gcn_gather<<<Nc, Hc, 0, stream>>>(Hbuf, offs, col, dis, b0, xA);
    // Layer 1
    k_gemm<Hc><<<Nc / 16, 256, 0, stream>>>(xA, W1, nullptr, Hbuf, Hc, 0);
    k_gcn_gather<<<Nc, Hc, 0, stream>>>(Hbuf, offs, col, dis, b1, xA);
    // Layer 2
    k_gemm<Hc><<<Nc / 16, 256, 0, stream>>>(xA, W2, nullptr, Hbuf, Hc, 0);
    k_gcn_gather<<<Nc, Hc, 0, stream>>>(Hbuf, offs, col, dis, b2, xA);

    // user_final / paper_final
    k_gemm<Hc><<<Uc / 16, 256, 0, stream>>>(xA, Wu, bu, uf, Dc, 0);
    k_gemm<Hc><<<Pc / 16, 256, 0, stream>>>(xA + (size_t)Uc * Hc, Wp, bp, pf, Dc, 0);

    // Au = uf @ Wq1[0:128,:] + bq1 ; Ap = pf @ Wq1[128:,:]
    k_gemm<Dc><<<Uc / 16, 256, 0, stream>>>(uf, Wq1, bq1, Au, Hc, 0);
    k_gemm<Dc><<<Pc / 16, 256, 0, stream>>>(pf, Wq1 + (size_t)Dc * Hc, nullptr, Ap, Hc, 0);

    // predictor
    dim3 pg(Uc / 64, Pc / 64);
    k_pred<<<pg, 256, 0, stream>>>(Au, Ap, Wq2, bq2, pred);
}

// Round 2
// 316.555 us; speedup vs baseline: 1.7926x; 1.7926x over previous
//
#include <hip/hip_runtime.h>
#include <math.h>

// Problem constants
constexpr int Uc = 512;
constexpr int Pc = 1024;
constexpr int Dc = 128;
constexpr int Hc = 256;
constexpr int Ec = 98304;
constexpr int Nc = 1536;   // U + P

// ---------------- CSR construction ----------------

__global__ void k_zero_deg(int* deg) {
    int i = blockIdx.x * 256 + threadIdx.x;
    if (i < Nc) deg[i] = 0;
}

__global__ void k_hist(const int* __restrict__ dst, int* __restrict__ deg) {
    int e = blockIdx.x * 256 + threadIdx.x;
    if (e < Ec) atomicAdd(&deg[dst[e]], 1);
}

// Single block, 256 threads. Exclusive scan of per-node edge counts (6 per thread),
// also computes dis[i] = rsqrt(deg_edges + 1)  (the +1 is the self-loop).
__global__ void k_scan(const int* __restrict__ deg, int* __restrict__ offs,
                       int* __restrict__ cursor, float* __restrict__ dis) {
    __shared__ int partial[256];
    int t = threadIdx.x;
    int base = t * 6;
    int v[6];
    int s = 0;
#pragma unroll
    for (int j = 0; j < 6; j++) { v[j] = deg[base + j]; s += v[j]; }
    partial[t] = s;
    __syncthreads();
    for (int off = 1; off < 256; off <<= 1) {
        int x = partial[t];
        int y = (t >= off) ? partial[t - off] : 0;
        __syncthreads();
        partial[t] = x + y;
        __syncthreads();
    }
    int run = (t == 0) ? 0 : partial[t - 1];
#pragma unroll
    for (int j = 0; j < 6; j++) {
        offs[base + j] = run;
        cursor[base + j] = run;
        dis[base + j] = rsqrtf((float)(v[j] + 1));
        run += v[j];
    }
    if (t == 255) offs[Nc] = run;
}

__global__ void k_scatter(const int* __restrict__ src, const int* __restrict__ dst,
                          int* __restrict__ cursor, int* __restrict__ col) {
    int e = blockIdx.x * 256 + threadIdx.x;
    if (e < Ec) {
        int p = atomicAdd(&cursor[dst[e]], 1);
        col[p] = src[e];
    }
}

// ---------------- node features ----------------

__global__ void k_build_x(const int* __restrict__ uid, const int* __restrict__ pid,
                          const float* __restrict__ ue, const float* __restrict__ pe,
                          float* __restrict__ x0) {
    int i = blockIdx.x;       // node
    int t = threadIdx.x;      // 128 threads = D
    if (i < Uc) x0[i * Dc + t] = ue[uid[i] * Dc + t];
    else        x0[i * Dc + t] = pe[pid[i - Uc] * Dc + t];
}

// ---------------- tiled GEMM:  Y[n,M] = X[n,K] @ W[K,M] (+bias) (+relu) ----------
// 64x64 tile per 256-thread block, 4x4 register tile per thread, KC=32 LDS chunks.
// Grid: (n/64, M/64). n, M multiples of 64; K multiple of 32.
template <int K>
__global__ void k_gemm64(const float* __restrict__ X, const float* __restrict__ W,
                         const float* __restrict__ bias, float* __restrict__ Y,
                         int M, int do_relu) {
    constexpr int KC = 32;
    constexpr int LDP = 68;  // padded row stride: 272 B (16B-aligned, breaks bank stride)
    __shared__ float xs[KC][LDP];   // xs[kk][row]  (transposed)
    __shared__ float ws[KC][LDP];   // ws[kk][col]
    int t = threadIdx.x;
    int r0 = blockIdx.x * 64;
    int c0 = blockIdx.y * 64;
    int tu = t >> 4, tp = t & 15;
    float acc[4][4] = {};

    for (int k0 = 0; k0 < K; k0 += KC) {
        __syncthreads();
        // stage X[r0:r0+64, k0:k0+32] -> xs[kk][row], float4 global reads
        {
            int idx = t;  // 512 float4s total, 2 per thread
#pragma unroll
            for (int it = 0; it < 2; it++, idx += 256) {
                int row = idx >> 3, q = idx & 7;
                const float4 v = *(const float4*)&X[(size_t)(r0 + row) * K + k0 + q * 4];
                xs[q * 4 + 0][row] = v.x;
                xs[q * 4 + 1][row] = v.y;
                xs[q * 4 + 2][row] = v.z;
                xs[q * 4 + 3][row] = v.w;
            }
        }
        // stage W[k0:k0+32, c0:c0+64] -> ws[kk][col], float4 in and out
        {
            int idx = t;
#pragma unroll
            for (int it = 0; it < 2; it++, idx += 256) {
                int kk = idx >> 4, q = idx & 15;
                const float4 v = *(const float4*)&W[(size_t)(k0 + kk) * M + c0 + q * 4];
                *(float4*)&ws[kk][q * 4] = v;
            }
        }
        __syncthreads();
#pragma unroll 8
        for (int kk = 0; kk < KC; kk++) {
            float4 a = *(const float4*)&xs[kk][tu * 4];
            float4 b = *(const float4*)&ws[kk][tp * 4];
            float av[4] = {a.x, a.y, a.z, a.w};
            float bv[4] = {b.x, b.y, b.z, b.w};
#pragma unroll
            for (int r = 0; r < 4; r++)
#pragma unroll
                for (int c = 0; c < 4; c++)
                    acc[r][c] += av[r] * bv[c];
        }
    }

    float bv4[4];
#pragma unroll
    for (int c = 0; c < 4; c++) bv4[c] = bias ? bias[c0 + tp * 4 + c] : 0.f;
#pragma unroll
    for (int r = 0; r < 4; r++) {
        int row = r0 + tu * 4 + r;
        float4 o;
        float* po = (float*)&o;
#pragma unroll
        for (int c = 0; c < 4; c++) {
            float v = acc[r][c] + bv4[c];
            po[c] = do_relu ? fmaxf(v, 0.f) : v;
        }
        *(float4*)&Y[(size_t)row * M + c0 + tp * 4] = o;
    }
}

// ---------------- GCN gather (SpMM by dst) + bias + relu ----------------
// One block per node, 256 threads (one per feature).
__global__ void k_gcn_gather(const float* __restrict__ h, const int* __restrict__ offs,
                             const int* __restrict__ col, const float* __restrict__ dis,
                             const float* __restrict__ bias, float* __restrict__ out) {
    int i = blockIdx.x;
    int f = threadIdx.x;
    float di = dis[i];
    float acc = h[i * Hc + f] * di * di;   // self-loop
    int e = offs[i], e1 = offs[i + 1];
    for (; e + 4 <= e1; e += 4) {
        int s0 = col[e], s1 = col[e + 1], s2 = col[e + 2], s3 = col[e + 3];
        float n0 = dis[s0] * di, n1 = dis[s1] * di, n2 = dis[s2] * di, n3 = dis[s3] * di;
        float h0 = h[s0 * Hc + f], h1 = h[s1 * Hc + f];
        float h2 = h[s2 * Hc + f], h3 = h[s3 * Hc + f];
        acc += h0 * n0 + h1 * n1 + h2 * n2 + h3 * n3;
    }
    for (; e < e1; e++) {
        int s = col[e];
        acc += h[s * Hc + f] * (dis[s] * di);
    }
    out[i * Hc + f] = fmaxf(acc + bias[f], 0.f);
}

// ---------------- predictor: pred[u,p] = sigmoid( sum_k relu(Au+Ap)*w + bq2 ) ------
__global__ void k_pred(const float* __restrict__ Au, const float* __restrict__ Ap,
                       const float* __restrict__ Wq2, const float* __restrict__ bq2,
                       float* __restrict__ out) {
    __shared__ float au_s[64][33];
    __shared__ float ap_s[64][33];
    __shared__ float w_s[Hc];
    int t = threadIdx.x;
    int ub = blockIdx.x * 64;
    int pb = blockIdx.y * 64;
    int tu = t >> 4, tp = t & 15;
    float acc[4][4] = {};
    w_s[t] = Wq2[t];
    for (int k0 = 0; k0 < Hc; k0 += 32) {
        __syncthreads();
        for (int idx = t; idx < 64 * 32; idx += 256) {
            int r = idx >> 5, kk = idx & 31;
            au_s[r][kk] = Au[(ub + r) * Hc + k0 + kk];
            ap_s[r][kk] = Ap[(pb + r) * Hc + k0 + kk];
        }
        __syncthreads();
#pragma unroll 8
        for (int kk = 0; kk < 32; kk++) {
            float w = w_s[k0 + kk];
            float av[4], pv[4];
#pragma unroll
            for (int r = 0; r < 4; r++) av[r] = au_s[tu * 4 + r][kk];
#pragma unroll
            for (int c = 0; c < 4; c++) pv[c] = ap_s[tp * 4 + c][kk];
#pragma unroll
            for (int r = 0; r < 4; r++)
#pragma unroll
                for (int c = 0; c < 4; c++)
                    acc[r][c] += fmaxf(av[r] + pv[c], 0.f) * w;
        }
    }
    float bq = bq2[0];
#pragma unroll
    for (int r = 0; r < 4; r++) {
        int u = ub + tu * 4 + r;
        float4 o;
        float* po = (float*)&o;
#pragma unroll
        for (int c = 0; c < 4; c++) {
            float s = acc[r][c] + bq;
            po[c] = 1.f / (1.f + __expf(-s));
        }
        *(float4*)&out[u * Pc + pb + tp * 4] = o;
    }
}

// ---------------- launcher ----------------

extern "C" void kernel_launch(void* const* d_in, const int* in_sizes, int n_in,
                              void* d_out, int out_size, void* d_ws, size_t ws_size,
                              hipStream_t stream) {
    const int*   uid = (const int*)d_in[0];
    const int*   pid = (const int*)d_in[1];
    const int*   ei  = (const int*)d_in[2];   // [2,E]: src = ei[0..E), dst = ei[E..2E)
    const float* ue  = (const float*)d_in[4];
    const float* pe  = (const float*)d_in[5];
    const float* W0  = (const float*)d_in[6];  const float* b0 = (const float*)d_in[7];
    const float* W1  = (const float*)d_in[8];  const float* b1 = (const float*)d_in[9];
    const float* W2  = (const float*)d_in[10]; const float* b2 = (const float*)d_in[11];
    const float* Wu  = (const float*)d_in[12]; const float* bu = (const float*)d_in[13];
    const float* Wp  = (const float*)d_in[14]; const float* bp = (const float*)d_in[15];
    const float* Wq1 = (const float*)d_in[16]; const float* bq1 = (const float*)d_in[17];
    const float* Wq2 = (const float*)d_in[18]; const float* bq2 = (const float*)d_in[19];

    const int* e_src = ei;
    const int* e_dst = ei + Ec;

    char* w = (char*)d_ws;
    auto alloc = [&](size_t bytes) { char* p = w; w += (bytes + 255) & ~size_t(255); return p; };
    int*   deg    = (int*)alloc(Nc * 4);
    int*   offs   = (int*)alloc((Nc + 1) * 4);
    int*   cursor = (int*)alloc(Nc * 4);
    int*   col    = (int*)alloc(Ec * 4);
    float* dis    = (float*)alloc(Nc * 4);
    float* x0     = (float*)alloc((size_t)Nc * Dc * 4);
    float* xA     = (float*)alloc((size_t)Nc * Hc * 4);
    float* Hbuf   = (float*)alloc((size_t)Nc * Hc * 4);
    float* uf     = (float*)alloc((size_t)Uc * Dc * 4);
    float* pf     = (float*)alloc((size_t)Pc * Dc * 4);
    float* Au     = (float*)alloc((size_t)Uc * Hc * 4);
    float* Ap     = (float*)alloc((size_t)Pc * Hc * 4);
    float* pred   = (float*)d_out;

    // CSR by dst
    k_zero_deg<<<(Nc + 255) / 256, 256, 0, stream>>>(deg);
    k_hist<<<Ec / 256, 256, 0, stream>>>(e_dst, deg);
    k_scan<<<1, 256, 0, stream>>>(deg, offs, cursor, dis);
    k_scatter<<<Ec / 256, 256, 0, stream>>>(e_src, e_dst, cursor, col);

    // x0 = [user_emb[uid]; paper_emb[pid]]
    k_build_x<<<Nc, Dc, 0, stream>>>(uid, pid, ue, pe, x0);

    // Layer 0: H = x0 @ W0 ; xA = relu(gather(H) + b0)
    k_gemm64<Dc><<<dim3(Nc / 64, Hc / 64), 256, 0, stream>>>(x0, W0, nullptr, Hbuf, Hc, 0);
    k_gcn_gather<<<Nc, Hc, 0, stream>>>(Hbuf, offs, col, dis, b0, xA);
    // Layer 1
    k_gemm64<Hc><<<dim3(Nc / 64, Hc / 64), 256, 0, stream>>>(xA, W1, nullptr, Hbuf, Hc, 0);
    k_gcn_gather<<<Nc, Hc, 0, stream>>>(Hbuf, offs, col, dis, b1, xA);
    // Layer 2
    k_gemm64<Hc><<<dim3(Nc / 64, Hc / 64), 256, 0, stream>>>(xA, W2, nullptr, Hbuf, Hc, 0);
    k_gcn_gather<<<Nc, Hc, 0, stream>>>(Hbuf, offs, col, dis, b2, xA);

    // user_final / paper_final
    k_gemm64<Hc><<<dim3(Uc / 64, Dc / 64), 256, 0, stream>>>(xA, Wu, bu, uf, Dc, 0);
    k_gemm64<Hc><<<dim3(Pc / 64, Dc / 64), 256, 0, stream>>>(xA + (size_t)Uc * Hc, Wp, bp, pf, Dc, 0);

    // Au = uf @ Wq1[0:128,:] + bq1 ; Ap = pf @ Wq1[128:,:]
    k_gemm64<Dc><<<dim3(Uc / 64, Hc / 64), 256, 0, stream>>>(uf, Wq1, bq1, Au, Hc, 0);
    k_gemm64<Dc><<<dim3(Pc / 64, Hc / 64), 256, 0, stream>>>(pf, Wq1 + (size_t)Dc * Hc, nullptr, Ap, Hc, 0);

    // predictor
    dim3 pg(Uc / 64, Pc / 64);
    k_pred<<<pg, 256, 0, stream>>>(Au, Ap, Wq2, bq2, pred);
}